// Round 4
// baseline (520.580 us; speedup 1.0000x reference)
//
#include <hip/hip_runtime.h>
#include <cstdint>
#include <cstddef>

#define B_    4096
#define LAT   64
#define FRAME 512
#define HID   1024
#define NE    8
#define GH    128
#define IN1   576   // LAT + FRAME
#define IN2   1088  // LAT + HID

typedef __bf16 bf16x8 __attribute__((ext_vector_type(8)));
typedef _Float16 half8 __attribute__((ext_vector_type(8)));
typedef float  f32x4  __attribute__((ext_vector_type(4)));

// round-to-nearest-even fp32 -> bf16
__device__ inline unsigned short f2bf(float f) {
  union { float f; uint32_t u; } c; c.f = f;
  uint32_t u = c.u;
  return (unsigned short)((u + 0x7FFFu + ((u >> 16) & 1u)) >> 16);
}

// async global->LDS, 16B per lane; LDS dest = wave-uniform base + lane*16
__device__ inline void async16(const void* g, void* l) {
  __builtin_amdgcn_global_load_lds(
      (__attribute__((address_space(1))) void*)(void*)g,
      (__attribute__((address_space(3))) void*)l, 16, 0, 0);
}

__device__ inline float elu(float v) { return v > 0.f ? v : expm1f(v); }

// ---- prep: gw1 [576][128] -> gw1T f16 [128][576]; gw2 [128][128] -> gw2T ----
__global__ __launch_bounds__(256) void prep_gatew(
    const float* __restrict__ gw1, const float* __restrict__ gw2,
    _Float16* __restrict__ gw1T, _Float16* __restrict__ gw2T)
{
  __shared__ float t[32][33];
  const int tx = threadIdx.x, ty = threadIdx.y;
  int bx = blockIdx.x;
  const float* in; _Float16* out; int K, N, kt, nt;
  if (bx < 72) { in = gw1; out = gw1T; K = 576; N = 128; kt = bx >> 2; nt = bx & 3; }
  else { bx -= 72; in = gw2; out = gw2T; K = 128; N = 128; kt = bx >> 2; nt = bx & 3; }
  const int k0 = kt * 32, n0 = nt * 32;
  for (int it = 0; it < 4; ++it)
    t[ty + it * 8][tx] = in[(size_t)(k0 + ty + it * 8) * N + n0 + tx];
  __syncthreads();
  for (int it = 0; it < 4; ++it)
    out[(size_t)(n0 + ty + it * 8) * K + k0 + tx] = (_Float16)t[tx][ty + it * 8];
}

// ---------------- gate MLP via f16 MFMA -> coef [B, 8] fp32 ----------------
// 32 blocks x 256 thr; block = 128 rows. Wave w owns rows w*32..w*32+31.
__global__ __launch_bounds__(256) void gate_mfma(
    const float* __restrict__ z, const float* __restrict__ c,
    const _Float16* __restrict__ gw1T,   // [128][576]
    const _Float16* __restrict__ gw2T,   // [128][128]
    const float* __restrict__ gb1, const float* __restrict__ gb2,
    const float* __restrict__ gw3, const float* __restrict__ gb3,
    float* __restrict__ coef)
{
  __shared__ _Float16 h_lds[128][136];   // +8 pad: row stride 272B -> conflict-free-ish
  __shared__ float    h2_lds[128][129];  // +1 pad for scalar column reads
  __shared__ float    gw3s[128 * 8];
  const int tid = threadIdx.x;
  const int wave = tid >> 6, lane = tid & 63;
  const int quad = lane >> 4, l16 = lane & 15;
  const int r0 = blockIdx.x * 128;

  for (int i = tid; i < 128 * 8; i += 256) gw3s[i] = gw3[i];

  // ---- layer 1: [128 x 576] @ gw1 -> h [128 x 128] ----
  f32x4 acc[2][8];
  #pragma unroll
  for (int mt = 0; mt < 2; ++mt)
    #pragma unroll
    for (int nt = 0; nt < 8; ++nt)
      #pragma unroll
      for (int r = 0; r < 4; ++r) acc[mt][nt][r] = 0.f;

  #pragma unroll 2
  for (int s = 0; s < 18; ++s) {
    const int k0 = s * 32;
    half8 af[2];
    #pragma unroll
    for (int mt = 0; mt < 2; ++mt) {
      const size_t row = r0 + wave * 32 + mt * 16 + l16;
      const float* src = (k0 < LAT) ? z + row * LAT + k0 + quad * 8
                                    : c + row * FRAME + (k0 - LAT) + quad * 8;
      f32x4 lo = *(const f32x4*)src, hi = *(const f32x4*)(src + 4);
      #pragma unroll
      for (int j = 0; j < 4; ++j) { af[mt][j] = (_Float16)lo[j]; af[mt][j + 4] = (_Float16)hi[j]; }
    }
    half8 bfr[8];
    #pragma unroll
    for (int nt = 0; nt < 8; ++nt)
      bfr[nt] = *(const half8*)(gw1T + (size_t)(nt * 16 + l16) * 576 + k0 + quad * 8);
    #pragma unroll
    for (int mt = 0; mt < 2; ++mt)
      #pragma unroll
      for (int nt = 0; nt < 8; ++nt)
        acc[mt][nt] = __builtin_amdgcn_mfma_f32_16x16x32_f16(af[mt], bfr[nt], acc[mt][nt], 0, 0, 0);
  }
  #pragma unroll
  for (int mt = 0; mt < 2; ++mt)
    #pragma unroll
    for (int nt = 0; nt < 8; ++nt)
      #pragma unroll
      for (int r = 0; r < 4; ++r) {
        const int rowl = wave * 32 + mt * 16 + quad * 4 + r;
        const int col = nt * 16 + l16;
        h_lds[rowl][col] = (_Float16)elu(acc[mt][nt][r] + gb1[col]);
      }
  __syncthreads();

  // ---- layer 2: h @ gw2 -> h2 [128 x 128] ----
  f32x4 acc2[2][8];
  #pragma unroll
  for (int mt = 0; mt < 2; ++mt)
    #pragma unroll
    for (int nt = 0; nt < 8; ++nt)
      #pragma unroll
      for (int r = 0; r < 4; ++r) acc2[mt][nt][r] = 0.f;
  #pragma unroll
  for (int s = 0; s < 4; ++s) {
    const int k0 = s * 32;
    half8 af[2];
    #pragma unroll
    for (int mt = 0; mt < 2; ++mt)
      af[mt] = *(const half8*)&h_lds[wave * 32 + mt * 16 + l16][k0 + quad * 8];
    half8 bfr[8];
    #pragma unroll
    for (int nt = 0; nt < 8; ++nt)
      bfr[nt] = *(const half8*)(gw2T + (size_t)(nt * 16 + l16) * 128 + k0 + quad * 8);
    #pragma unroll
    for (int mt = 0; mt < 2; ++mt)
      #pragma unroll
      for (int nt = 0; nt < 8; ++nt)
        acc2[mt][nt] = __builtin_amdgcn_mfma_f32_16x16x32_f16(af[mt], bfr[nt], acc2[mt][nt], 0, 0, 0);
  }
  #pragma unroll
  for (int mt = 0; mt < 2; ++mt)
    #pragma unroll
    for (int nt = 0; nt < 8; ++nt)
      #pragma unroll
      for (int r = 0; r < 4; ++r) {
        const int rowl = wave * 32 + mt * 16 + quad * 4 + r;
        const int col = nt * 16 + l16;
        h2_lds[rowl][col] = elu(acc2[mt][nt][r] + gb2[col]);
      }
  __syncthreads();

  // ---- layer 3 + softmax: 2 threads per row, 4 experts each ----
  {
    const int row = tid >> 1, eh = (tid & 1) * 4;
    float l4[4];
    #pragma unroll
    for (int j = 0; j < 4; ++j) l4[j] = gb3[eh + j];
    for (int k = 0; k < 128; ++k) {
      const float hv = h2_lds[row][k];
      #pragma unroll
      for (int j = 0; j < 4; ++j) l4[j] += hv * gw3s[k * 8 + eh + j];
    }
    float m4 = fmaxf(fmaxf(l4[0], l4[1]), fmaxf(l4[2], l4[3]));
    const float M = fmaxf(m4, __shfl_xor(m4, 1));
    float e4[4], s = 0.f;
    #pragma unroll
    for (int j = 0; j < 4; ++j) { e4[j] = expf(l4[j] - M); s += e4[j]; }
    const float inv = 1.f / (s + __shfl_xor(s, 1));
    f32x4 o;
    #pragma unroll
    for (int j = 0; j < 4; ++j) o[j] = e4[j] * inv;
    *(f32x4*)&coef[(size_t)(r0 + row) * NE + eh] = o;
  }
}

// ---- weights [E][K][N] fp32 -> Wt [N][E*K] bf16 (B^T layout, e-major k') ----
__global__ __launch_bounds__(256) void transpose_cast_flat(
    const float* __restrict__ in, unsigned short* __restrict__ out, int K, int N)
{
  __shared__ float t[32][33];
  const int e = blockIdx.z;
  const int n0 = blockIdx.x * 32, k0 = blockIdx.y * 32;
  const float* ine = in + (size_t)e * K * N;
  const int tx = threadIdx.x, ty = threadIdx.y;
  for (int it = 0; it < 4; ++it)
    t[ty + it * 8][tx] = ine[(size_t)(k0 + ty + it * 8) * N + n0 + tx];
  __syncthreads();
  for (int it = 0; it < 4; ++it)
    out[(size_t)(n0 + ty + it * 8) * (NE * K) + (size_t)e * K + k0 + tx] =
        f2bf(t[tx][ty + it * 8]);
}

// ---- X'1[b, e*IN1 + j] = bf16(coef[b,e] * x0[b,j]),  x0 = [z | c] ----
__global__ __launch_bounds__(256) void build_xp1(
    const float* __restrict__ z, const float* __restrict__ c,
    const float* __restrict__ coef, unsigned short* __restrict__ xp)
{
  int idx = blockIdx.x * 256 + threadIdx.x;   // B_*IN1 exact
  int b = idx / IN1, j = idx - b * IN1;
  float v = (j < LAT) ? z[(size_t)b * LAT + j] : c[(size_t)b * FRAME + (j - LAT)];
  const float* cf = coef + (size_t)b * NE;
  unsigned short* row = xp + (size_t)b * (NE * IN1) + j;
  #pragma unroll
  for (int e = 0; e < NE; ++e) row[(size_t)e * IN1] = f2bf(cf[e] * v);
}

// ---- GEMM: part[b][n] += sum_{k chunk z} X'[b,k'] * Wt[n,k'] (atomic k-split) ----
template<int KP, int NOUT, int KSTEPS>
__global__ __launch_bounds__(256, 4) void gemm_bt(
    const unsigned short* __restrict__ Xp,   // [B_][KP]
    const unsigned short* __restrict__ Wt,   // [NOUT][KP]
    float* __restrict__ part)                // [B_][NOUT], pre-zeroed
{
  __shared__ __align__(16) unsigned short As[128 * 64];
  __shared__ __align__(16) unsigned short Bs[128 * 64];
  const int tid = threadIdx.x;
  const int wave = tid >> 6, lane = tid & 63;
  const int wm = wave & 1, wn = wave >> 1;
  const int quad = lane >> 4, l16 = lane & 15;
  const int bm0 = blockIdx.x * 128, bn0 = blockIdx.y * 128;
  const int kbase = blockIdx.z * (KSTEPS * 64);

  f32x4 acc[4][4];
  #pragma unroll
  for (int mi = 0; mi < 4; ++mi)
    #pragma unroll
    for (int ni = 0; ni < 4; ++ni)
      #pragma unroll
      for (int r = 0; r < 4; ++r) acc[mi][ni][r] = 0.f;

  const int srow  = wave * 8 + (lane >> 3);                  // + it*32
  const int skoff = (((lane & 7) ^ ((lane >> 3) & 7)) * 8);  // swizzled src granule

  for (int ki = 0; ki < KSTEPS; ++ki) {
    const int k0 = kbase + ki * 64;
    #pragma unroll
    for (int it = 0; it < 4; ++it) {
      async16(Xp + (size_t)(bm0 + it * 32 + srow) * KP + k0 + skoff,
              &As[it * 2048 + wave * 512]);
      async16(Wt + (size_t)(bn0 + it * 32 + srow) * KP + k0 + skoff,
              &Bs[it * 2048 + wave * 512]);
    }
    __syncthreads();
    #pragma unroll
    for (int ks = 0; ks < 64; ks += 32) {
      bf16x8 af[4], bv[4];
      #pragma unroll
      for (int mi = 0; mi < 4; ++mi) {
        const int r = wm * 64 + mi * 16 + l16;
        const int g = (ks / 8 + quad) ^ (r & 7);
        af[mi] = *(const bf16x8*)&As[r * 64 + g * 8];
      }
      #pragma unroll
      for (int ni = 0; ni < 4; ++ni) {
        const int r = wn * 64 + ni * 16 + l16;
        const int g = (ks / 8 + quad) ^ (r & 7);
        bv[ni] = *(const bf16x8*)&Bs[r * 64 + g * 8];
      }
      #pragma unroll
      for (int mi = 0; mi < 4; ++mi)
        #pragma unroll
        for (int ni = 0; ni < 4; ++ni)
          acc[mi][ni] = __builtin_amdgcn_mfma_f32_16x16x32_bf16(
              af[mi], bv[ni], acc[mi][ni], 0, 0, 0);
    }
    __syncthreads();
  }

  #pragma unroll
  for (int mi = 0; mi < 4; ++mi)
    #pragma unroll
    for (int r = 0; r < 4; ++r) {
      const int m_loc = wm * 64 + mi * 16 + quad * 4 + r;
      #pragma unroll
      for (int ni = 0; ni < 4; ++ni) {
        const int n_loc = wn * 64 + ni * 16 + l16;
        atomicAdd(&part[(size_t)(bm0 + m_loc) * NOUT + bn0 + n_loc], acc[mi][ni][r]);
      }
    }
}

// ---- epilogue+expand: act = ELU(part + coef@bias); X'[b,e*IN2+j] = bf16(coef*val) ----
__global__ __launch_bounds__(256) void expand_xp(
    const float* __restrict__ part,   // [B_][HID]
    const float* __restrict__ bias,   // [NE][HID]
    const float* __restrict__ z,
    const float* __restrict__ coef,
    unsigned short* __restrict__ xp)  // [B_][NE*IN2]
{
  int idx = blockIdx.x * 256 + threadIdx.x;   // B_*IN2 exact
  int b = idx / IN2, j = idx - b * IN2;
  const float* cf = coef + (size_t)b * NE;
  float cl[NE];
  #pragma unroll
  for (int e = 0; e < NE; ++e) cl[e] = cf[e];
  float v;
  if (j < LAT) {
    v = z[(size_t)b * LAT + j];
  } else {
    int h = j - LAT;
    v = part[(size_t)b * HID + h];
    #pragma unroll
    for (int e = 0; e < NE; ++e) v += cl[e] * bias[(size_t)e * HID + h];
    v = elu(v);
  }
  unsigned short* row = xp + (size_t)b * (NE * IN2) + j;
  #pragma unroll
  for (int e = 0; e < NE; ++e) row[(size_t)e * IN2] = f2bf(cl[e] * v);
}

// ---- final: out = part + coef@bias2 ----
__global__ __launch_bounds__(256) void final_out(
    const float* __restrict__ part,   // [B_][FRAME]
    const float* __restrict__ bias2,  // [NE][FRAME]
    const float* __restrict__ coef,
    float* __restrict__ out)
{
  int idx = blockIdx.x * 256 + threadIdx.x;   // B_*FRAME exact
  int b = idx / FRAME, n = idx - b * FRAME;
  float v = part[idx];
  const float* cf = coef + (size_t)b * NE;
  #pragma unroll
  for (int e = 0; e < NE; ++e) v += cf[e] * bias2[(size_t)e * FRAME + n];
  out[idx] = v;
}

// ============================ launch ============================

extern "C" void kernel_launch(void* const* d_in, const int* in_sizes, int n_in,
                              void* d_out, int out_size, void* d_ws, size_t ws_size,
                              hipStream_t stream)
{
  const float* z   = (const float*)d_in[0];
  const float* c   = (const float*)d_in[1];
  const float* w0  = (const float*)d_in[2];
  const float* b0  = (const float*)d_in[3];
  const float* w1  = (const float*)d_in[4];
  const float* b1  = (const float*)d_in[5];
  const float* w2  = (const float*)d_in[6];
  const float* b2  = (const float*)d_in[7];
  const float* gw1 = (const float*)d_in[8];
  const float* gb1 = (const float*)d_in[9];
  const float* gw2 = (const float*)d_in[10];
  const float* gb2 = (const float*)d_in[11];
  const float* gw3 = (const float*)d_in[12];
  const float* gb3 = (const float*)d_in[13];
  float* out = (float*)d_out;
  char* ws = (char*)d_ws;

  // workspace (proven ws_size >= 122,814,464 from round 3): total 106,217,472
  float*          coef = (float*)         (ws + 0);           // 131,072
  unsigned short* Xp   = (unsigned short*)(ws + 131072);      // 71,303,168
  unsigned short* Wt   = (unsigned short*)(ws + 71434240);    // 17,825,792
  float*          part = (float*)         (ws + 89260032);    // 16,777,216
  _Float16*       gw1T = (_Float16*)      (ws + 106037248);   // 147,456
  _Float16*       gw2T = (_Float16*)      (ws + 106184704);   // 32,768

  prep_gatew<<<88, dim3(32, 8), 0, stream>>>(gw1, gw2, gw1T, gw2T);
  gate_mfma<<<32, 256, 0, stream>>>(z, c, gw1T, gw2T, gb1, gb2, gw3, gb3, coef);
  build_xp1<<<(B_ * IN1) / 256, 256, 0, stream>>>(z, c, coef, Xp);

  // layer 1: K' = 4608 (72 ksteps), N = 1024, split 4 x 18
  transpose_cast_flat<<<dim3(HID / 32, IN1 / 32, NE), dim3(32, 8), 0, stream>>>(w0, Wt, IN1, HID);
  hipMemsetAsync(part, 0, (size_t)B_ * HID * 4, stream);
  gemm_bt<NE * IN1, HID, 18><<<dim3(32, 8, 4), 256, 0, stream>>>(Xp, Wt, part);
  expand_xp<<<(B_ * IN2) / 256, 256, 0, stream>>>(part, b0, z, coef, Xp);

  // layer 2: K' = 8704 (136 ksteps), N = 1024, split 4 x 34
  transpose_cast_flat<<<dim3(HID / 32, IN2 / 32, NE), dim3(32, 8), 0, stream>>>(w1, Wt, IN2, HID);
  hipMemsetAsync(part, 0, (size_t)B_ * HID * 4, stream);
  gemm_bt<NE * IN2, HID, 34><<<dim3(32, 8, 4), 256, 0, stream>>>(Xp, Wt, part);
  expand_xp<<<(B_ * IN2) / 256, 256, 0, stream>>>(part, b1, z, coef, Xp);

  // layer 3: K' = 8704, N = 512, split 8 x 17
  transpose_cast_flat<<<dim3(FRAME / 32, IN2 / 32, NE), dim3(32, 8), 0, stream>>>(w2, Wt, IN2, FRAME);
  hipMemsetAsync(part, 0, (size_t)B_ * FRAME * 4, stream);
  gemm_bt<NE * IN2, FRAME, 17><<<dim3(32, 4, 8), 256, 0, stream>>>(Xp, Wt, part);
  final_out<<<(B_ * FRAME) / 256, 256, 0, stream>>>(part, b2, coef, out);
}

// Round 5
// 423.448 us; speedup vs baseline: 1.2294x; 1.2294x over previous
//
#include <hip/hip_runtime.h>
#include <cstdint>
#include <cstddef>

#define B_    4096
#define LAT   64
#define FRAME 512
#define HID   1024
#define NE    8
#define GH    128
#define IN1   576   // LAT + FRAME
#define IN2   1088  // LAT + HID

typedef __bf16 bf16x8 __attribute__((ext_vector_type(8)));
typedef _Float16 half8 __attribute__((ext_vector_type(8)));
typedef float  f32x4  __attribute__((ext_vector_type(4)));
typedef unsigned short us4 __attribute__((ext_vector_type(4)));

// round-to-nearest-even fp32 -> bf16
__device__ inline unsigned short f2bf(float f) {
  union { float f; uint32_t u; } c; c.f = f;
  uint32_t u = c.u;
  return (unsigned short)((u + 0x7FFFu + ((u >> 16) & 1u)) >> 16);
}

// async global->LDS, 16B per lane; LDS dest = wave-uniform base + lane*16
__device__ inline void async16(const void* g, void* l) {
  __builtin_amdgcn_global_load_lds(
      (__attribute__((address_space(1))) void*)(void*)g,
      (__attribute__((address_space(3))) void*)l, 16, 0, 0);
}

__device__ inline float elu(float v) { return v > 0.f ? v : expm1f(v); }

// ---- prep: gw1 [576][128] -> gw1T f16 [128][576]; gw2 [128][128] -> gw2T ----
__global__ __launch_bounds__(256) void prep_gatew(
    const float* __restrict__ gw1, const float* __restrict__ gw2,
    _Float16* __restrict__ gw1T, _Float16* __restrict__ gw2T)
{
  __shared__ float t[32][33];
  const int tx = threadIdx.x, ty = threadIdx.y;
  int bx = blockIdx.x;
  const float* in; _Float16* out; int K, N, kt, nt;
  if (bx < 72) { in = gw1; out = gw1T; K = 576; N = 128; kt = bx >> 2; nt = bx & 3; }
  else { bx -= 72; in = gw2; out = gw2T; K = 128; N = 128; kt = bx >> 2; nt = bx & 3; }
  const int k0 = kt * 32, n0 = nt * 32;
  for (int it = 0; it < 4; ++it)
    t[ty + it * 8][tx] = in[(size_t)(k0 + ty + it * 8) * N + n0 + tx];
  __syncthreads();
  for (int it = 0; it < 4; ++it)
    out[(size_t)(n0 + ty + it * 8) * K + k0 + tx] = (_Float16)t[tx][ty + it * 8];
}

// ---------------- gate MLP via f16 MFMA -> coef [B, 8] fp32 ----------------
__global__ __launch_bounds__(256) void gate_mfma(
    const float* __restrict__ z, const float* __restrict__ c,
    const _Float16* __restrict__ gw1T,   // [128][576]
    const _Float16* __restrict__ gw2T,   // [128][128]
    const float* __restrict__ gb1, const float* __restrict__ gb2,
    const float* __restrict__ gw3, const float* __restrict__ gb3,
    float* __restrict__ coef)
{
  __shared__ _Float16 h_lds[128][136];
  __shared__ float    h2_lds[128][129];
  __shared__ float    gw3s[128 * 8];
  const int tid = threadIdx.x;
  const int wave = tid >> 6, lane = tid & 63;
  const int quad = lane >> 4, l16 = lane & 15;
  const int r0 = blockIdx.x * 128;

  for (int i = tid; i < 128 * 8; i += 256) gw3s[i] = gw3[i];

  f32x4 acc[2][8];
  #pragma unroll
  for (int mt = 0; mt < 2; ++mt)
    #pragma unroll
    for (int nt = 0; nt < 8; ++nt)
      #pragma unroll
      for (int r = 0; r < 4; ++r) acc[mt][nt][r] = 0.f;

  #pragma unroll 2
  for (int s = 0; s < 18; ++s) {
    const int k0 = s * 32;
    half8 af[2];
    #pragma unroll
    for (int mt = 0; mt < 2; ++mt) {
      const size_t row = r0 + wave * 32 + mt * 16 + l16;
      const float* src = (k0 < LAT) ? z + row * LAT + k0 + quad * 8
                                    : c + row * FRAME + (k0 - LAT) + quad * 8;
      f32x4 lo = *(const f32x4*)src, hi = *(const f32x4*)(src + 4);
      #pragma unroll
      for (int j = 0; j < 4; ++j) { af[mt][j] = (_Float16)lo[j]; af[mt][j + 4] = (_Float16)hi[j]; }
    }
    half8 bfr[8];
    #pragma unroll
    for (int nt = 0; nt < 8; ++nt)
      bfr[nt] = *(const half8*)(gw1T + (size_t)(nt * 16 + l16) * 576 + k0 + quad * 8);
    #pragma unroll
    for (int mt = 0; mt < 2; ++mt)
      #pragma unroll
      for (int nt = 0; nt < 8; ++nt)
        acc[mt][nt] = __builtin_amdgcn_mfma_f32_16x16x32_f16(af[mt], bfr[nt], acc[mt][nt], 0, 0, 0);
  }
  #pragma unroll
  for (int mt = 0; mt < 2; ++mt)
    #pragma unroll
    for (int nt = 0; nt < 8; ++nt)
      #pragma unroll
      for (int r = 0; r < 4; ++r) {
        const int rowl = wave * 32 + mt * 16 + quad * 4 + r;
        const int col = nt * 16 + l16;
        h_lds[rowl][col] = (_Float16)elu(acc[mt][nt][r] + gb1[col]);
      }
  __syncthreads();

  f32x4 acc2[2][8];
  #pragma unroll
  for (int mt = 0; mt < 2; ++mt)
    #pragma unroll
    for (int nt = 0; nt < 8; ++nt)
      #pragma unroll
      for (int r = 0; r < 4; ++r) acc2[mt][nt][r] = 0.f;
  #pragma unroll
  for (int s = 0; s < 4; ++s) {
    const int k0 = s * 32;
    half8 af[2];
    #pragma unroll
    for (int mt = 0; mt < 2; ++mt)
      af[mt] = *(const half8*)&h_lds[wave * 32 + mt * 16 + l16][k0 + quad * 8];
    half8 bfr[8];
    #pragma unroll
    for (int nt = 0; nt < 8; ++nt)
      bfr[nt] = *(const half8*)(gw2T + (size_t)(nt * 16 + l16) * 128 + k0 + quad * 8);
    #pragma unroll
    for (int mt = 0; mt < 2; ++mt)
      #pragma unroll
      for (int nt = 0; nt < 8; ++nt)
        acc2[mt][nt] = __builtin_amdgcn_mfma_f32_16x16x32_f16(af[mt], bfr[nt], acc2[mt][nt], 0, 0, 0);
  }
  #pragma unroll
  for (int mt = 0; mt < 2; ++mt)
    #pragma unroll
    for (int nt = 0; nt < 8; ++nt)
      #pragma unroll
      for (int r = 0; r < 4; ++r) {
        const int rowl = wave * 32 + mt * 16 + quad * 4 + r;
        const int col = nt * 16 + l16;
        h2_lds[rowl][col] = elu(acc2[mt][nt][r] + gb2[col]);
      }
  __syncthreads();

  {
    const int row = tid >> 1, eh = (tid & 1) * 4;
    float l4[4];
    #pragma unroll
    for (int j = 0; j < 4; ++j) l4[j] = gb3[eh + j];
    for (int k = 0; k < 128; ++k) {
      const float hv = h2_lds[row][k];
      #pragma unroll
      for (int j = 0; j < 4; ++j) l4[j] += hv * gw3s[k * 8 + eh + j];
    }
    float m4 = fmaxf(fmaxf(l4[0], l4[1]), fmaxf(l4[2], l4[3]));
    const float M = fmaxf(m4, __shfl_xor(m4, 1));
    float e4[4], s = 0.f;
    #pragma unroll
    for (int j = 0; j < 4; ++j) { e4[j] = expf(l4[j] - M); s += e4[j]; }
    const float inv = 1.f / (s + __shfl_xor(s, 1));
    f32x4 o;
    #pragma unroll
    for (int j = 0; j < 4; ++j) o[j] = e4[j] * inv;
    *(f32x4*)&coef[(size_t)(r0 + row) * NE + eh] = o;
  }
}

// ---- weights [E][K][N] fp32 -> Wt [N][E*K] bf16 (B^T layout, e-major k') ----
__global__ __launch_bounds__(256) void transpose_cast_flat(
    const float* __restrict__ in, unsigned short* __restrict__ out, int K, int N)
{
  __shared__ float t[32][33];
  const int e = blockIdx.z;
  const int n0 = blockIdx.x * 32, k0 = blockIdx.y * 32;
  const float* ine = in + (size_t)e * K * N;
  const int tx = threadIdx.x, ty = threadIdx.y;
  for (int it = 0; it < 4; ++it)
    t[ty + it * 8][tx] = ine[(size_t)(k0 + ty + it * 8) * N + n0 + tx];
  __syncthreads();
  for (int it = 0; it < 4; ++it)
    out[(size_t)(n0 + ty + it * 8) * (NE * K) + (size_t)e * K + k0 + tx] =
        f2bf(t[tx][ty + it * 8]);
}

// ---- build X'1: one block per row b; coalesced ushort4 stores per expert ----
__global__ __launch_bounds__(256) void build_xp1(
    const float* __restrict__ z, const float* __restrict__ c,
    const float* __restrict__ coef, unsigned short* __restrict__ xp)
{
  __shared__ float x0[IN1];
  __shared__ float cfs[NE];
  const int b = blockIdx.x, tid = threadIdx.x;
  if (tid < NE) cfs[tid] = coef[(size_t)b * NE + tid];
  for (int j = tid; j < IN1; j += 256)
    x0[j] = (j < LAT) ? z[(size_t)b * LAT + j] : c[(size_t)b * FRAME + (j - LAT)];
  __syncthreads();
  unsigned short* row = xp + (size_t)b * (NE * IN1);
  #pragma unroll
  for (int e = 0; e < NE; ++e) {
    const float cf = cfs[e];
    // IN1*2 = 1152 B per segment = 144 x 8B; 256 threads -> 1 iter (guarded)
    if (tid < IN1 / 4) {
      const int j = tid * 4;
      us4 o;
      #pragma unroll
      for (int q = 0; q < 4; ++q) o[q] = f2bf(cf * x0[j + q]);
      *(us4*)(row + (size_t)e * IN1 + j) = o;
    }
  }
}

// ---- GEMM: part[z][b][n] = sum_{k chunk z} X'[b,k'] * Wt[n,k'] ----
template<int KP, int NOUT, int KSTEPS>
__global__ __launch_bounds__(256, 3) void gemm_bt(
    const unsigned short* __restrict__ Xp,   // [B_][KP]
    const unsigned short* __restrict__ Wt,   // [NOUT][KP]
    float* __restrict__ part)                // [KSPLIT][B_][NOUT]
{
  __shared__ __align__(16) unsigned short As[128 * 64];
  __shared__ __align__(16) unsigned short Bs[128 * 64];
  const int tid = threadIdx.x;
  const int wave = tid >> 6, lane = tid & 63;
  const int wm = wave & 1, wn = wave >> 1;
  const int quad = lane >> 4, l16 = lane & 15;
  const int bm0 = blockIdx.x * 128, bn0 = blockIdx.y * 128;
  const int kbase = blockIdx.z * (KSTEPS * 64);

  f32x4 acc[4][4];
  #pragma unroll
  for (int mi = 0; mi < 4; ++mi)
    #pragma unroll
    for (int ni = 0; ni < 4; ++ni)
      #pragma unroll
      for (int r = 0; r < 4; ++r) acc[mi][ni][r] = 0.f;

  const int srow  = wave * 8 + (lane >> 3);
  const int skoff = (((lane & 7) ^ ((lane >> 3) & 7)) * 8);

  for (int ki = 0; ki < KSTEPS; ++ki) {
    const int k0 = kbase + ki * 64;
    #pragma unroll
    for (int it = 0; it < 4; ++it) {
      async16(Xp + (size_t)(bm0 + it * 32 + srow) * KP + k0 + skoff,
              &As[it * 2048 + wave * 512]);
      async16(Wt + (size_t)(bn0 + it * 32 + srow) * KP + k0 + skoff,
              &Bs[it * 2048 + wave * 512]);
    }
    __syncthreads();
    #pragma unroll
    for (int ks = 0; ks < 64; ks += 32) {
      bf16x8 af[4], bv[4];
      #pragma unroll
      for (int mi = 0; mi < 4; ++mi) {
        const int r = wm * 64 + mi * 16 + l16;
        const int g = (ks / 8 + quad) ^ (r & 7);
        af[mi] = *(const bf16x8*)&As[r * 64 + g * 8];
      }
      #pragma unroll
      for (int ni = 0; ni < 4; ++ni) {
        const int r = wn * 64 + ni * 16 + l16;
        const int g = (ks / 8 + quad) ^ (r & 7);
        bv[ni] = *(const bf16x8*)&Bs[r * 64 + g * 8];
      }
      #pragma unroll
      for (int mi = 0; mi < 4; ++mi)
        #pragma unroll
        for (int ni = 0; ni < 4; ++ni)
          acc[mi][ni] = __builtin_amdgcn_mfma_f32_16x16x32_bf16(
              af[mi], bv[ni], acc[mi][ni], 0, 0, 0);
    }
    __syncthreads();
  }

  float* po = part + (size_t)blockIdx.z * B_ * NOUT;
  #pragma unroll
  for (int mi = 0; mi < 4; ++mi)
    #pragma unroll
    for (int r = 0; r < 4; ++r) {
      const int m_loc = wm * 64 + mi * 16 + quad * 4 + r;
      #pragma unroll
      for (int ni = 0; ni < 4; ++ni) {
        const int n_loc = wn * 64 + ni * 16 + l16;
        po[(size_t)(bm0 + m_loc) * NOUT + bn0 + n_loc] = acc[mi][ni][r];
      }
    }
}

// ---- expand: one block per row b; act row in LDS; coalesced ushort4 stores ----
__global__ __launch_bounds__(256) void expand_xp(
    const float* __restrict__ part,   // [2][B_][HID]
    const float* __restrict__ bias,   // [NE][HID]
    const float* __restrict__ z,
    const float* __restrict__ coef,
    unsigned short* __restrict__ xp)  // [B_][NE*IN2]
{
  __shared__ float act[IN2];
  __shared__ float cfs[NE];
  const int b = blockIdx.x, tid = threadIdx.x;
  if (tid < NE) cfs[tid] = coef[(size_t)b * NE + tid];
  for (int j = tid; j < LAT; j += 256) act[j] = z[(size_t)b * LAT + j];
  __syncthreads();
  for (int h = tid; h < HID; h += 256) {
    float v = part[(size_t)b * HID + h] + part[(size_t)B_ * HID + (size_t)b * HID + h];
    #pragma unroll
    for (int e = 0; e < NE; ++e) v += cfs[e] * bias[(size_t)e * HID + h];
    act[LAT + h] = elu(v);
  }
  __syncthreads();
  unsigned short* row = xp + (size_t)b * (NE * IN2);
  #pragma unroll
  for (int e = 0; e < NE; ++e) {
    const float cf = cfs[e];
    // IN2*2 = 2176 B per segment = 272 x 8B units
    for (int u = tid; u < IN2 / 4; u += 256) {
      const int j = u * 4;
      us4 o;
      #pragma unroll
      for (int q = 0; q < 4; ++q) o[q] = f2bf(cf * act[j + q]);
      *(us4*)(row + (size_t)e * IN2 + j) = o;
    }
  }
}

// ---- final: out[b,n] = sum_s part[s][b][n] + coef@bias2 ----
__global__ __launch_bounds__(256) void final_out(
    const float* __restrict__ part,   // [4][B_][FRAME]
    const float* __restrict__ bias2,  // [NE][FRAME]
    const float* __restrict__ coef,
    float* __restrict__ out)
{
  int idx = blockIdx.x * 256 + threadIdx.x;   // B_*FRAME exact
  int b = idx / FRAME, n = idx - b * FRAME;
  float v = 0.f;
  #pragma unroll
  for (int s = 0; s < 4; ++s)
    v += part[(size_t)s * B_ * FRAME + idx];
  const float* cf = coef + (size_t)b * NE;
  #pragma unroll
  for (int e = 0; e < NE; ++e) v += cf[e] * bias2[(size_t)e * FRAME + n];
  out[idx] = v;
}

// ============================ launch ============================

extern "C" void kernel_launch(void* const* d_in, const int* in_sizes, int n_in,
                              void* d_out, int out_size, void* d_ws, size_t ws_size,
                              hipStream_t stream)
{
  const float* z   = (const float*)d_in[0];
  const float* c   = (const float*)d_in[1];
  const float* w0  = (const float*)d_in[2];
  const float* b0  = (const float*)d_in[3];
  const float* w1  = (const float*)d_in[4];
  const float* b1  = (const float*)d_in[5];
  const float* w2  = (const float*)d_in[6];
  const float* b2  = (const float*)d_in[7];
  const float* gw1 = (const float*)d_in[8];
  const float* gb1 = (const float*)d_in[9];
  const float* gw2 = (const float*)d_in[10];
  const float* gb2 = (const float*)d_in[11];
  const float* gw3 = (const float*)d_in[12];
  const float* gb3 = (const float*)d_in[13];
  float* out = (float*)d_out;
  char* ws = (char*)d_ws;

  // workspace (proven ws_size >= 122,814,464): total used = 122,814,464
  float*          coef = (float*)         (ws + 0);           // 131,072
  unsigned short* Xp   = (unsigned short*)(ws + 131072);      // 71,303,168
  unsigned short* Wt   = (unsigned short*)(ws + 71434240);    // 17,825,792
  float*          part = (float*)         (ws + 89260032);    // 33,554,432
  // gate weight scratch aliases the part region (used strictly before gemm L1)
  _Float16*       gw1T = (_Float16*)      (ws + 89260032);    // 147,456
  _Float16*       gw2T = (_Float16*)      (ws + 89407488);    // 32,768

  prep_gatew<<<88, dim3(32, 8), 0, stream>>>(gw1, gw2, gw1T, gw2T);
  gate_mfma<<<32, 256, 0, stream>>>(z, c, gw1T, gw2T, gb1, gb2, gw3, gb3, coef);
  build_xp1<<<B_, 256, 0, stream>>>(z, c, coef, Xp);

  // layer 1: K' = 4608, N = 1024, split 2 x 36
  transpose_cast_flat<<<dim3(HID / 32, IN1 / 32, NE), dim3(32, 8), 0, stream>>>(w0, Wt, IN1, HID);
  gemm_bt<NE * IN1, HID, 36><<<dim3(32, 8, 2), 256, 0, stream>>>(Xp, Wt, part);
  expand_xp<<<B_, 256, 0, stream>>>(part, b0, z, coef, Xp);

  // layer 2: K' = 8704, N = 1024, split 2 x 68
  transpose_cast_flat<<<dim3(HID / 32, IN2 / 32, NE), dim3(32, 8), 0, stream>>>(w1, Wt, IN2, HID);
  gemm_bt<NE * IN2, HID, 68><<<dim3(32, 8, 2), 256, 0, stream>>>(Xp, Wt, part);
  expand_xp<<<B_, 256, 0, stream>>>(part, b1, z, coef, Xp);

  // layer 3: K' = 8704, N = 512, split 4 x 34
  transpose_cast_flat<<<dim3(FRAME / 32, IN2 / 32, NE), dim3(32, 8), 0, stream>>>(w2, Wt, IN2, FRAME);
  gemm_bt<NE * IN2, FRAME, 34><<<dim3(32, 4, 4), 256, 0, stream>>>(Xp, Wt, part);
  final_out<<<(B_ * FRAME) / 256, 256, 0, stream>>>(part, b2, coef, out);
}

// Round 6
// 380.867 us; speedup vs baseline: 1.3668x; 1.1118x over previous
//
#include <hip/hip_runtime.h>
#include <cstdint>
#include <cstddef>

#define B_    4096
#define LAT   64
#define FRAME 512
#define HID   1024
#define NE    8
#define GH    128
#define IN1   576   // LAT + FRAME
#define IN2   1088  // LAT + HID

typedef _Float16 half8 __attribute__((ext_vector_type(8)));
typedef float  f32x4  __attribute__((ext_vector_type(4)));

// async global->LDS, 16B per lane; LDS dest = wave-uniform base + lane*16
__device__ inline void async16(const void* g, void* l) {
  __builtin_amdgcn_global_load_lds(
      (__attribute__((address_space(1))) void*)(void*)g,
      (__attribute__((address_space(3))) void*)l, 16, 0, 0);
}

__device__ inline float elu(float v) { return v > 0.f ? v : expm1f(v); }

// ---- prep: gw1 [576][128] -> gw1T f16 [128][576]; gw2 [128][128] -> gw2T ----
__global__ __launch_bounds__(256) void prep_gatew(
    const float* __restrict__ gw1, const float* __restrict__ gw2,
    _Float16* __restrict__ gw1T, _Float16* __restrict__ gw2T)
{
  __shared__ float t[32][33];
  const int tx = threadIdx.x, ty = threadIdx.y;
  int bx = blockIdx.x;
  const float* in; _Float16* out; int K, N, kt, nt;
  if (bx < 72) { in = gw1; out = gw1T; K = 576; N = 128; kt = bx >> 2; nt = bx & 3; }
  else { bx -= 72; in = gw2; out = gw2T; K = 128; N = 128; kt = bx >> 2; nt = bx & 3; }
  const int k0 = kt * 32, n0 = nt * 32;
  for (int it = 0; it < 4; ++it)
    t[ty + it * 8][tx] = in[(size_t)(k0 + ty + it * 8) * N + n0 + tx];
  __syncthreads();
  for (int it = 0; it < 4; ++it)
    out[(size_t)(n0 + ty + it * 8) * K + k0 + tx] = (_Float16)t[tx][ty + it * 8];
}

// ---------------- gate MLP via f16 MFMA -> coef [B, 8] fp32 ----------------
__global__ __launch_bounds__(256) void gate_mfma(
    const float* __restrict__ z, const float* __restrict__ c,
    const _Float16* __restrict__ gw1T,   // [128][576]
    const _Float16* __restrict__ gw2T,   // [128][128]
    const float* __restrict__ gb1, const float* __restrict__ gb2,
    const float* __restrict__ gw3, const float* __restrict__ gb3,
    float* __restrict__ coef)
{
  __shared__ _Float16 h_lds[128][136];
  __shared__ float    h2_lds[128][129];
  __shared__ float    gw3s[128 * 8];
  const int tid = threadIdx.x;
  const int wave = tid >> 6, lane = tid & 63;
  const int quad = lane >> 4, l16 = lane & 15;
  const int r0 = blockIdx.x * 128;

  for (int i = tid; i < 128 * 8; i += 256) gw3s[i] = gw3[i];

  f32x4 acc[2][8];
  #pragma unroll
  for (int mt = 0; mt < 2; ++mt)
    #pragma unroll
    for (int nt = 0; nt < 8; ++nt)
      #pragma unroll
      for (int r = 0; r < 4; ++r) acc[mt][nt][r] = 0.f;

  #pragma unroll 2
  for (int s = 0; s < 18; ++s) {
    const int k0 = s * 32;
    half8 af[2];
    #pragma unroll
    for (int mt = 0; mt < 2; ++mt) {
      const size_t row = r0 + wave * 32 + mt * 16 + l16;
      const float* src = (k0 < LAT) ? z + row * LAT + k0 + quad * 8
                                    : c + row * FRAME + (k0 - LAT) + quad * 8;
      f32x4 lo = *(const f32x4*)src, hi = *(const f32x4*)(src + 4);
      #pragma unroll
      for (int j = 0; j < 4; ++j) { af[mt][j] = (_Float16)lo[j]; af[mt][j + 4] = (_Float16)hi[j]; }
    }
    half8 bfr[8];
    #pragma unroll
    for (int nt = 0; nt < 8; ++nt)
      bfr[nt] = *(const half8*)(gw1T + (size_t)(nt * 16 + l16) * 576 + k0 + quad * 8);
    #pragma unroll
    for (int mt = 0; mt < 2; ++mt)
      #pragma unroll
      for (int nt = 0; nt < 8; ++nt)
        acc[mt][nt] = __builtin_amdgcn_mfma_f32_16x16x32_f16(af[mt], bfr[nt], acc[mt][nt], 0, 0, 0);
  }
  #pragma unroll
  for (int mt = 0; mt < 2; ++mt)
    #pragma unroll
    for (int nt = 0; nt < 8; ++nt)
      #pragma unroll
      for (int r = 0; r < 4; ++r) {
        const int rowl = wave * 32 + mt * 16 + quad * 4 + r;
        const int col = nt * 16 + l16;
        h_lds[rowl][col] = (_Float16)elu(acc[mt][nt][r] + gb1[col]);
      }
  __syncthreads();

  f32x4 acc2[2][8];
  #pragma unroll
  for (int mt = 0; mt < 2; ++mt)
    #pragma unroll
    for (int nt = 0; nt < 8; ++nt)
      #pragma unroll
      for (int r = 0; r < 4; ++r) acc2[mt][nt][r] = 0.f;
  #pragma unroll
  for (int s = 0; s < 4; ++s) {
    const int k0 = s * 32;
    half8 af[2];
    #pragma unroll
    for (int mt = 0; mt < 2; ++mt)
      af[mt] = *(const half8*)&h_lds[wave * 32 + mt * 16 + l16][k0 + quad * 8];
    half8 bfr[8];
    #pragma unroll
    for (int nt = 0; nt < 8; ++nt)
      bfr[nt] = *(const half8*)(gw2T + (size_t)(nt * 16 + l16) * 128 + k0 + quad * 8);
    #pragma unroll
    for (int mt = 0; mt < 2; ++mt)
      #pragma unroll
      for (int nt = 0; nt < 8; ++nt)
        acc2[mt][nt] = __builtin_amdgcn_mfma_f32_16x16x32_f16(af[mt], bfr[nt], acc2[mt][nt], 0, 0, 0);
  }
  #pragma unroll
  for (int mt = 0; mt < 2; ++mt)
    #pragma unroll
    for (int nt = 0; nt < 8; ++nt)
      #pragma unroll
      for (int r = 0; r < 4; ++r) {
        const int rowl = wave * 32 + mt * 16 + quad * 4 + r;
        const int col = nt * 16 + l16;
        h2_lds[rowl][col] = elu(acc2[mt][nt][r] + gb2[col]);
      }
  __syncthreads();

  {
    const int row = tid >> 1, eh = (tid & 1) * 4;
    float l4[4];
    #pragma unroll
    for (int j = 0; j < 4; ++j) l4[j] = gb3[eh + j];
    for (int k = 0; k < 128; ++k) {
      const float hv = h2_lds[row][k];
      #pragma unroll
      for (int j = 0; j < 4; ++j) l4[j] += hv * gw3s[k * 8 + eh + j];
    }
    float m4 = fmaxf(fmaxf(l4[0], l4[1]), fmaxf(l4[2], l4[3]));
    const float M = fmaxf(m4, __shfl_xor(m4, 1));
    float e4[4], s = 0.f;
    #pragma unroll
    for (int j = 0; j < 4; ++j) { e4[j] = expf(l4[j] - M); s += e4[j]; }
    const float inv = 1.f / (s + __shfl_xor(s, 1));
    f32x4 o;
    #pragma unroll
    for (int j = 0; j < 4; ++j) o[j] = e4[j] * inv;
    *(f32x4*)&coef[(size_t)(r0 + row) * NE + eh] = o;
  }
}

// ---- weights [E][K][N] fp32 -> [E][N][K] f16, 64x64 tiles ----
__global__ __launch_bounds__(256) void transpose_cast_e(
    const float* __restrict__ in, _Float16* __restrict__ out, int K, int N)
{
  __shared__ float t[64][65];
  const int e = blockIdx.z;
  const int k0 = blockIdx.x * 64, n0 = blockIdx.y * 64;
  const float* ine = in + (size_t)e * K * N;
  _Float16* oute = out + (size_t)e * N * K;
  const int tx = threadIdx.x, ty = threadIdx.y;   // (64, 4)
  #pragma unroll
  for (int it = 0; it < 16; ++it) {
    const int k = it * 4 + ty;
    t[k][tx] = ine[(size_t)(k0 + k) * N + n0 + tx];
  }
  __syncthreads();
  #pragma unroll
  for (int it = 0; it < 16; ++it) {
    const int n = it * 4 + ty;
    oute[(size_t)(n0 + n) * K + k0 + tx] = (_Float16)t[tx][n];
  }
}

// ---- x1 f16 = [z | c] ----
__global__ __launch_bounds__(256) void build_x1(
    const float* __restrict__ z, const float* __restrict__ c,
    _Float16* __restrict__ x1)
{
  int idx = blockIdx.x * 256 + threadIdx.x;   // B_*IN1 exact
  int b = idx / IN1, j = idx - b * IN1;
  float v = (j < LAT) ? z[(size_t)b * LAT + j] : c[(size_t)b * FRAME + (j - LAT)];
  x1[idx] = (_Float16)v;
}

// -------- MoE GEMM, compact-X f16, coef folded into A-fragments --------
// X [B][KDIM] f16; Wt [NE][NOUT][KDIM] f16; blockIdx.z = expert-group of EG.
// k0-outer: A staged once per k0 (reused across EG experts via registers);
// B double-buffered per expert (staging overlaps compute).
// part[z] = sum_{e in group} coef_e*(X@W_e + bias_e)  (bias in-chunk).
template<int KDIM, int NOUT, int EG>
__global__ __launch_bounds__(256, 2) void gemm_moe(
    const _Float16* __restrict__ X,
    const _Float16* __restrict__ Wt,
    const float* __restrict__ coef,     // [B][8]
    const float* __restrict__ bias,     // [8][NOUT]
    float* __restrict__ part)           // [ESPLIT][B][NOUT]
{
  __shared__ __align__(16) _Float16 As[128 * 64];
  __shared__ __align__(16) _Float16 Bs[2][128 * 64];
  __shared__ float coefS[128 * EG];
  __shared__ float biasS[EG * 128];

  const int tid = threadIdx.x;
  const int wave = tid >> 6, lane = tid & 63;
  const int wm = wave & 1, wn = wave >> 1;
  const int quad = lane >> 4, l16 = lane & 15;
  const int bm0 = blockIdx.x * 128, bn0 = blockIdx.y * 128;
  const int ebase = blockIdx.z * EG;

  for (int i = tid; i < 128 * EG; i += 256)
    coefS[i] = coef[(size_t)(bm0 + i / EG) * NE + ebase + (i % EG)];
  for (int i = tid; i < EG * 128; i += 256)
    biasS[i] = bias[(size_t)(ebase + i / 128) * NOUT + bn0 + (i % 128)];
  __syncthreads();

  // per-lane coef for A-scaling: A-fragment row = wm*64 + mi*16 + l16
  _Float16 ch[4][EG];
  #pragma unroll
  for (int mi = 0; mi < 4; ++mi)
    #pragma unroll
    for (int e = 0; e < EG; ++e)
      ch[mi][e] = (_Float16)coefS[(wm * 64 + mi * 16 + l16) * EG + e];

  f32x4 acc[4][4];
  #pragma unroll
  for (int mi = 0; mi < 4; ++mi)
    #pragma unroll
    for (int ni = 0; ni < 4; ++ni)
      #pragma unroll
      for (int r = 0; r < 4; ++r) acc[mi][ni][r] = 0.f;

  const int srow  = wave * 8 + (lane >> 3);                  // + it*32
  const int skoff = (((lane & 7) ^ ((lane >> 3) & 7)) * 8);  // swizzled src granule

  constexpr int K0S = KDIM / 64;
  for (int k0i = 0; k0i < K0S; ++k0i) {
    const int k0 = k0i * 64;
    // stage A (once per k0) and B for first expert of the group
    #pragma unroll
    for (int it = 0; it < 4; ++it)
      async16(X + (size_t)(bm0 + it * 32 + srow) * KDIM + k0 + skoff,
              &As[it * 2048 + wave * 512]);
    {
      const size_t eoff = (size_t)ebase * NOUT * KDIM;
      #pragma unroll
      for (int it = 0; it < 4; ++it)
        async16(Wt + eoff + (size_t)(bn0 + it * 32 + srow) * KDIM + k0 + skoff,
                &Bs[0][it * 2048 + wave * 512]);
    }
    __syncthreads();

    // A fragments for this k0, reused across the expert group
    half8 af[2][4];
    #pragma unroll
    for (int ks = 0; ks < 2; ++ks)
      #pragma unroll
      for (int mi = 0; mi < 4; ++mi) {
        const int r = wm * 64 + mi * 16 + l16;
        const int g = (ks * 4 + quad) ^ (r & 7);
        af[ks][mi] = *(const half8*)&As[r * 64 + g * 8];
      }

    #pragma unroll
    for (int eo = 0; eo < EG; ++eo) {
      if (eo + 1 < EG) {   // prefetch next expert's B tile into other buffer
        const size_t eoff = (size_t)(ebase + eo + 1) * NOUT * KDIM;
        #pragma unroll
        for (int it = 0; it < 4; ++it)
          async16(Wt + eoff + (size_t)(bn0 + it * 32 + srow) * KDIM + k0 + skoff,
                  &Bs[(eo + 1) & 1][it * 2048 + wave * 512]);
      }
      const _Float16* bsrc = Bs[eo & 1];
      #pragma unroll
      for (int ks = 0; ks < 2; ++ks) {
        half8 bv[4];
        #pragma unroll
        for (int ni = 0; ni < 4; ++ni) {
          const int r = wn * 64 + ni * 16 + l16;
          const int g = (ks * 4 + quad) ^ (r & 7);
          bv[ni] = *(const half8*)&bsrc[r * 64 + g * 8];
        }
        #pragma unroll
        for (int mi = 0; mi < 4; ++mi) {
          const half8 afs = af[ks][mi] * ch[mi][eo];
          #pragma unroll
          for (int ni = 0; ni < 4; ++ni)
            acc[mi][ni] = __builtin_amdgcn_mfma_f32_16x16x32_f16(
                afs, bv[ni], acc[mi][ni], 0, 0, 0);
        }
      }
      __syncthreads();   // drains prefetch + protects buffer reuse
    }
  }

  // epilogue: + group's coef@bias; write partial (deterministic)
  float* po = part + (size_t)blockIdx.z * B_ * NOUT;
  #pragma unroll
  for (int mi = 0; mi < 4; ++mi)
    #pragma unroll
    for (int r = 0; r < 4; ++r) {
      const int m_loc = wm * 64 + mi * 16 + quad * 4 + r;
      #pragma unroll
      for (int ni = 0; ni < 4; ++ni) {
        const int n_loc = wn * 64 + ni * 16 + l16;
        float v = acc[mi][ni][r];
        #pragma unroll
        for (int e = 0; e < EG; ++e)
          v += coefS[m_loc * EG + e] * biasS[e * 128 + n_loc];
        po[(size_t)(bm0 + m_loc) * NOUT + bn0 + n_loc] = v;
      }
    }
}

// ---- expand: x_next[b][j] = f16( j<64 ? z : elu(sum_s part[s]) ) ----
template<int NS>
__global__ __launch_bounds__(256) void expand_x(
    const float* __restrict__ part,   // [NS][B_][HID]
    const float* __restrict__ z,
    _Float16* __restrict__ xn)        // [B_][IN2]
{
  int idx = blockIdx.x * 256 + threadIdx.x;   // B_*IN2 exact
  int b = idx / IN2, j = idx - b * IN2;
  float v;
  if (j < LAT) {
    v = z[(size_t)b * LAT + j];
  } else {
    const int h = j - LAT;
    v = 0.f;
    #pragma unroll
    for (int s = 0; s < NS; ++s)
      v += part[(size_t)s * B_ * HID + (size_t)b * HID + h];
    v = elu(v);
  }
  xn[idx] = (_Float16)v;
}

// ---- final: out = sum_s part[s] (bias already folded per chunk) ----
template<int NS>
__global__ __launch_bounds__(256) void final_out(
    const float* __restrict__ part,   // [NS][B_][FRAME]
    float* __restrict__ out)
{
  int idx = blockIdx.x * 256 + threadIdx.x;   // B_*FRAME exact
  float v = 0.f;
  #pragma unroll
  for (int s = 0; s < NS; ++s)
    v += part[(size_t)s * B_ * FRAME + idx];
  out[idx] = v;
}

// ============================ launch ============================

extern "C" void kernel_launch(void* const* d_in, const int* in_sizes, int n_in,
                              void* d_out, int out_size, void* d_ws, size_t ws_size,
                              hipStream_t stream)
{
  const float* z   = (const float*)d_in[0];
  const float* c   = (const float*)d_in[1];
  const float* w0  = (const float*)d_in[2];
  const float* b0  = (const float*)d_in[3];
  const float* w1  = (const float*)d_in[4];
  const float* b1  = (const float*)d_in[5];
  const float* w2  = (const float*)d_in[6];
  const float* b2  = (const float*)d_in[7];
  const float* gw1 = (const float*)d_in[8];
  const float* gb1 = (const float*)d_in[9];
  const float* gw2 = (const float*)d_in[10];
  const float* gb2 = (const float*)d_in[11];
  const float* gw3 = (const float*)d_in[12];
  const float* gb3 = (const float*)d_in[13];
  float* out = (float*)d_out;
  char* ws = (char*)d_ws;

  // workspace layout, total 92,585,984 bytes (< proven 122,814,464)
  float*    coef = (float*)    (ws + 0);           //   131,072
  _Float16* x1   = (_Float16*) (ws + 131072);      // 4,718,592
  _Float16* x2   = (_Float16*) (ws + 4849664);     // 8,912,896
  _Float16* x3   = (_Float16*) (ws + 13762560);    // 8,912,896
  _Float16* Wt0  = (_Float16*) (ws + 22675456);    // 9,437,184
  _Float16* Wt1  = (_Float16*) (ws + 32112640);    // 17,825,792
  _Float16* Wt2  = (_Float16*) (ws + 49938432);    // 8,912,896
  float*    part = (float*)    (ws + 58851328);    // 33,554,432
  _Float16* gw1T = (_Float16*) (ws + 92405760);    //   147,456
  _Float16* gw2T = (_Float16*) (ws + 92553216);    //    32,768

  prep_gatew<<<88, dim3(32, 8), 0, stream>>>(gw1, gw2, gw1T, gw2T);
  gate_mfma<<<32, 256, 0, stream>>>(z, c, gw1T, gw2T, gb1, gb2, gw3, gb3, coef);
  build_x1<<<(B_ * IN1) / 256, 256, 0, stream>>>(z, c, x1);
  transpose_cast_e<<<dim3(9, 16, NE), dim3(64, 4), 0, stream>>>(w0, Wt0, IN1, HID);
  transpose_cast_e<<<dim3(17, 16, NE), dim3(64, 4), 0, stream>>>(w1, Wt1, IN2, HID);
  transpose_cast_e<<<dim3(17, 8, NE), dim3(64, 4), 0, stream>>>(w2, Wt2, IN2, FRAME);

  // layer 1: K=576, N=1024, expert-split 2 x EG4
  gemm_moe<IN1, HID, 4><<<dim3(32, 8, 2), 256, 0, stream>>>(x1, Wt0, coef, b0, part);
  expand_x<2><<<(B_ * IN2) / 256, 256, 0, stream>>>(part, z, x2);

  // layer 2: K=1088, N=1024, expert-split 2 x EG4
  gemm_moe<IN2, HID, 4><<<dim3(32, 8, 2), 256, 0, stream>>>(x2, Wt1, coef, b1, part);
  expand_x<2><<<(B_ * IN2) / 256, 256, 0, stream>>>(part, z, x3);

  // layer 3: K=1088, N=512, expert-split 4 x EG2
  gemm_moe<IN2, FRAME, 2><<<dim3(32, 4, 4), 256, 0, stream>>>(x3, Wt2, coef, b2, part);
  final_out<4><<<(B_ * FRAME) / 256, 256, 0, stream>>>(part, out);
}

// Round 7
// 356.574 us; speedup vs baseline: 1.4599x; 1.0681x over previous
//
#include <hip/hip_runtime.h>
#include <cstdint>
#include <cstddef>

#define B_    4096
#define LAT   64
#define FRAME 512
#define HID   1024
#define NE    8
#define GH    128
#define IN1   576   // LAT + FRAME
#define IN2   1088  // LAT + HID

typedef _Float16 half8 __attribute__((ext_vector_type(8)));
typedef _Float16 half4 __attribute__((ext_vector_type(4)));
typedef float  f32x4  __attribute__((ext_vector_type(4)));
typedef float  f32x16 __attribute__((ext_vector_type(16)));

// async global->LDS, 16B per lane; LDS dest = wave-uniform base + lane*16
__device__ inline void async16(const void* g, void* l) {
  __builtin_amdgcn_global_load_lds(
      (__attribute__((address_space(1))) void*)(void*)g,
      (__attribute__((address_space(3))) void*)l, 16, 0, 0);
}

__device__ inline float elu(float v) { return v > 0.f ? v : expm1f(v); }

// ---- unified weight prep: all 5 transpose+casts (fp32 [K][N] -> f16 [N][K]) ----
// 64x64 tiles, flat 256 threads. blocks: w0 1152 | w1 2176 | w2 1088 | gw1 18 | gw2 4
__global__ __launch_bounds__(256) void prep_weights(
    const float* __restrict__ w0, const float* __restrict__ w1,
    const float* __restrict__ w2, const float* __restrict__ gw1,
    const float* __restrict__ gw2,
    _Float16* __restrict__ Wt0, _Float16* __restrict__ Wt1,
    _Float16* __restrict__ Wt2, _Float16* __restrict__ gw1T,
    _Float16* __restrict__ gw2T)
{
  __shared__ float t[64][65];
  int bid = blockIdx.x;
  const float* in; _Float16* out; int K, N, kt, nt;
  if (bid < 1152) {
    const int e = bid / 144, rem = bid % 144;
    K = IN1; N = HID; kt = rem / 16; nt = rem % 16;
    in = w0 + (size_t)e * K * N; out = Wt0 + (size_t)e * N * K;
  } else if (bid < 3328) {
    const int i = bid - 1152, e = i / 272, rem = i % 272;
    K = IN2; N = HID; kt = rem / 16; nt = rem % 16;
    in = w1 + (size_t)e * K * N; out = Wt1 + (size_t)e * N * K;
  } else if (bid < 4416) {
    const int i = bid - 3328, e = i / 136, rem = i % 136;
    K = IN2; N = FRAME; kt = rem / 8; nt = rem % 8;
    in = w2 + (size_t)e * K * N; out = Wt2 + (size_t)e * N * K;
  } else if (bid < 4434) {
    const int i = bid - 4416;
    K = IN1; N = GH; kt = i / 2; nt = i % 2;
    in = gw1; out = gw1T;
  } else {
    const int i = bid - 4434;
    K = GH; N = GH; kt = i / 2; nt = i % 2;
    in = gw2; out = gw2T;
  }
  const int k0 = kt * 64, n0 = nt * 64;
  const int tx = threadIdx.x & 63, ty = threadIdx.x >> 6;
  #pragma unroll
  for (int it = 0; it < 16; ++it) {
    const int k = it * 4 + ty;
    t[k][tx] = in[(size_t)(k0 + k) * N + n0 + tx];
  }
  __syncthreads();
  #pragma unroll
  for (int it = 0; it < 16; ++it) {
    const int n = it * 4 + ty;
    out[(size_t)(n0 + n) * K + k0 + tx] = (_Float16)t[tx][n];
  }
}

// ---------------- gate MLP via f16 MFMA -> coef [B, 8] fp32 ----------------
// 64 blocks x 256 thr; block = 64 rows; wave w owns rows w*16..w*16+15.
__global__ __launch_bounds__(256) void gate_mfma(
    const float* __restrict__ z, const float* __restrict__ c,
    const _Float16* __restrict__ gw1T,   // [128][576]
    const _Float16* __restrict__ gw2T,   // [128][128]
    const float* __restrict__ gb1, const float* __restrict__ gb2,
    const float* __restrict__ gw3, const float* __restrict__ gb3,
    float* __restrict__ coef)
{
  __shared__ _Float16 h_lds[64][136];
  __shared__ float    h2_lds[64][129];
  __shared__ float    gw3s[128 * 8];
  const int tid = threadIdx.x;
  const int wave = tid >> 6, lane = tid & 63;
  const int quad = lane >> 4, l16 = lane & 15;
  const int r0 = blockIdx.x * 64;

  for (int i = tid; i < 128 * 8; i += 256) gw3s[i] = gw3[i];

  // layer 1: [64 x 576] @ gw1 -> h [64 x 128]
  f32x4 acc[8];
  #pragma unroll
  for (int nt = 0; nt < 8; ++nt)
    #pragma unroll
    for (int r = 0; r < 4; ++r) acc[nt][r] = 0.f;

  #pragma unroll 2
  for (int s = 0; s < 18; ++s) {
    const int k0 = s * 32;
    half8 af;
    {
      const size_t row = r0 + wave * 16 + l16;
      const float* src = (k0 < LAT) ? z + row * LAT + k0 + quad * 8
                                    : c + row * FRAME + (k0 - LAT) + quad * 8;
      f32x4 lo = *(const f32x4*)src, hi = *(const f32x4*)(src + 4);
      #pragma unroll
      for (int j = 0; j < 4; ++j) { af[j] = (_Float16)lo[j]; af[j + 4] = (_Float16)hi[j]; }
    }
    half8 bfr[8];
    #pragma unroll
    for (int nt = 0; nt < 8; ++nt)
      bfr[nt] = *(const half8*)(gw1T + (size_t)(nt * 16 + l16) * 576 + k0 + quad * 8);
    #pragma unroll
    for (int nt = 0; nt < 8; ++nt)
      acc[nt] = __builtin_amdgcn_mfma_f32_16x16x32_f16(af, bfr[nt], acc[nt], 0, 0, 0);
  }
  #pragma unroll
  for (int nt = 0; nt < 8; ++nt)
    #pragma unroll
    for (int r = 0; r < 4; ++r) {
      const int rowl = wave * 16 + quad * 4 + r;
      const int col = nt * 16 + l16;
      h_lds[rowl][col] = (_Float16)elu(acc[nt][r] + gb1[col]);
    }
  __syncthreads();

  // layer 2: h @ gw2 -> h2 [64 x 128]
  f32x4 acc2[8];
  #pragma unroll
  for (int nt = 0; nt < 8; ++nt)
    #pragma unroll
    for (int r = 0; r < 4; ++r) acc2[nt][r] = 0.f;
  #pragma unroll
  for (int s = 0; s < 4; ++s) {
    const int k0 = s * 32;
    half8 af = *(const half8*)&h_lds[wave * 16 + l16][k0 + quad * 8];
    half8 bfr[8];
    #pragma unroll
    for (int nt = 0; nt < 8; ++nt)
      bfr[nt] = *(const half8*)(gw2T + (size_t)(nt * 16 + l16) * 128 + k0 + quad * 8);
    #pragma unroll
    for (int nt = 0; nt < 8; ++nt)
      acc2[nt] = __builtin_amdgcn_mfma_f32_16x16x32_f16(af, bfr[nt], acc2[nt], 0, 0, 0);
  }
  #pragma unroll
  for (int nt = 0; nt < 8; ++nt)
    #pragma unroll
    for (int r = 0; r < 4; ++r) {
      const int rowl = wave * 16 + quad * 4 + r;
      const int col = nt * 16 + l16;
      h2_lds[rowl][col] = elu(acc2[nt][r] + gb2[col]);
    }
  __syncthreads();

  // layer 3 + softmax: 4 threads/row, 2 experts each
  {
    const int row = tid >> 2, q = tid & 3;
    float l2v[2] = { gb3[2 * q], gb3[2 * q + 1] };
    for (int k = 0; k < 128; ++k) {
      const float hv = h2_lds[row][k];
      l2v[0] += hv * gw3s[k * 8 + 2 * q];
      l2v[1] += hv * gw3s[k * 8 + 2 * q + 1];
    }
    float m = fmaxf(l2v[0], l2v[1]);
    m = fmaxf(m, __shfl_xor(m, 1));
    m = fmaxf(m, __shfl_xor(m, 2));
    float e0 = expf(l2v[0] - m), e1 = expf(l2v[1] - m);
    float s = e0 + e1;
    s += __shfl_xor(s, 1);
    s += __shfl_xor(s, 2);
    const float inv = 1.f / s;
    float2 o = { e0 * inv, e1 * inv };
    *(float2*)&coef[(size_t)(r0 + row) * NE + 2 * q] = o;
  }
}

// ---- x1 f16 = [z | c], vectorized x4 ----
__global__ __launch_bounds__(256) void build_x1(
    const float* __restrict__ z, const float* __restrict__ c,
    _Float16* __restrict__ x1)
{
  const int idx4 = blockIdx.x * 256 + threadIdx.x;   // B_*IN1/4 exact
  const int b = idx4 / (IN1 / 4), j = (idx4 - b * (IN1 / 4)) * 4;
  f32x4 v = (j < LAT) ? *(const f32x4*)(z + (size_t)b * LAT + j)
                      : *(const f32x4*)(c + (size_t)b * FRAME + (j - LAT));
  half4 o;
  #pragma unroll
  for (int q = 0; q < 4; ++q) o[q] = (_Float16)v[q];
  *(half4*)(x1 + (size_t)b * IN1 + j) = o;
}

// -------- MoE GEMM: 32x32x16 f16 MFMA, coef folded into A-fragments --------
// A/B double-buffered; A(k0+1)+B0(k0+1) prefetched during last expert of k0.
// part[z] = sum_{e in group} coef_e*(X@W_e + bias_e)
template<int KDIM, int NOUT, int EG>
__global__ __launch_bounds__(256, 2) void gemm_moe(
    const _Float16* __restrict__ X,     // [B][KDIM]
    const _Float16* __restrict__ Wt,    // [NE][NOUT][KDIM]
    const float* __restrict__ coef,     // [B][8]
    const float* __restrict__ bias,     // [8][NOUT]
    float* __restrict__ part)           // [ESPLIT][B][NOUT]
{
  __shared__ __align__(16) _Float16 As[2][128 * 64];
  __shared__ __align__(16) _Float16 Bs[2][128 * 64];
  __shared__ float coefS[128 * EG];
  __shared__ float biasS[EG * 128];

  const int tid = threadIdx.x;
  const int wave = tid >> 6, lane = tid & 63;
  const int wm = wave & 1, wn = wave >> 1;
  const int l32 = lane & 31, khalf = lane >> 5;
  const int bm0 = blockIdx.x * 128, bn0 = blockIdx.y * 128;
  const int ebase = blockIdx.z * EG;

  for (int i = tid; i < 128 * EG; i += 256)
    coefS[i] = coef[(size_t)(bm0 + i / EG) * NE + ebase + (i % EG)];
  for (int i = tid; i < EG * 128; i += 256)
    biasS[i] = bias[(size_t)(ebase + (i >> 7)) * NOUT + bn0 + (i & 127)];

  const int srow  = wave * 8 + (lane >> 3);                  // + it*32
  const int skoff = (((lane & 7) ^ ((lane >> 3) & 7)) * 8);  // swizzled src granule

  #define STAGE_A(k0v, buf) \
    { _Pragma("unroll") \
      for (int it = 0; it < 4; ++it) \
        async16(X + (size_t)(bm0 + it * 32 + srow) * KDIM + (k0v) + skoff, \
                &(buf)[it * 2048 + wave * 512]); }
  #define STAGE_B(ev, k0v, buf) \
    { const size_t eoff = (size_t)(ev) * NOUT * KDIM; \
      _Pragma("unroll") \
      for (int it = 0; it < 4; ++it) \
        async16(Wt + eoff + (size_t)(bn0 + it * 32 + srow) * KDIM + (k0v) + skoff, \
                &(buf)[it * 2048 + wave * 512]); }

  STAGE_A(0, As[0]);
  STAGE_B(ebase, 0, Bs[0]);
  __syncthreads();

  // per-lane coef for A-scaling: A-fragment row = wm*64 + mi*32 + l32
  _Float16 ch[2][EG];
  #pragma unroll
  for (int mi = 0; mi < 2; ++mi)
    #pragma unroll
    for (int e = 0; e < EG; ++e)
      ch[mi][e] = (_Float16)coefS[(wm * 64 + mi * 32 + l32) * EG + e];

  f32x16 acc[2][2];
  #pragma unroll
  for (int mi = 0; mi < 2; ++mi)
    #pragma unroll
    for (int ni = 0; ni < 2; ++ni)
      #pragma unroll
      for (int r = 0; r < 16; ++r) acc[mi][ni][r] = 0.f;

  constexpr int K0S = KDIM / 64;
  for (int k0i = 0; k0i < K0S; ++k0i) {
    const int k0 = k0i * 64;
    const int ap = k0i & 1;
    // A fragments for this k0, reused across the expert group
    half8 af[4][2];
    #pragma unroll
    for (int ks = 0; ks < 4; ++ks)
      #pragma unroll
      for (int mi = 0; mi < 2; ++mi) {
        const int r = wm * 64 + mi * 32 + l32;
        const int g = (ks * 2 + khalf) ^ (r & 7);
        af[ks][mi] = *(const half8*)&As[ap][r * 64 + g * 8];
      }
    #pragma unroll
    for (int eo = 0; eo < EG; ++eo) {
      if (eo + 1 < EG) {
        STAGE_B(ebase + eo + 1, k0, Bs[(eo + 1) & 1]);
      } else if (k0i + 1 < K0S) {
        STAGE_A(k0 + 64, As[1 - ap]);
        STAGE_B(ebase, k0 + 64, Bs[EG & 1]);
      }
      const _Float16* bsrc = Bs[eo & 1];
      #pragma unroll
      for (int ks = 0; ks < 4; ++ks) {
        half8 bv[2];
        #pragma unroll
        for (int ni = 0; ni < 2; ++ni) {
          const int r = wn * 64 + ni * 32 + l32;
          const int g = (ks * 2 + khalf) ^ (r & 7);
          bv[ni] = *(const half8*)&bsrc[r * 64 + g * 8];
        }
        #pragma unroll
        for (int mi = 0; mi < 2; ++mi) {
          const half8 afs = af[ks][mi] * ch[mi][eo];
          #pragma unroll
          for (int ni = 0; ni < 2; ++ni)
            acc[mi][ni] = __builtin_amdgcn_mfma_f32_32x32x16_f16(
                afs, bv[ni], acc[mi][ni], 0, 0, 0);
        }
      }
      __syncthreads();
    }
  }
  #undef STAGE_A
  #undef STAGE_B

  // epilogue: + group's coef@bias; write partial.
  // 32x32 C/D layout: col = lane&31, row = (reg&3) + 8*(reg>>2) + 4*(lane>>5)
  float* po = part + (size_t)blockIdx.z * B_ * NOUT;
  #pragma unroll
  for (int mi = 0; mi < 2; ++mi)
    #pragma unroll
    for (int ni = 0; ni < 2; ++ni)
      #pragma unroll
      for (int reg = 0; reg < 16; ++reg) {
        const int row_l = (reg & 3) + 8 * (reg >> 2) + 4 * khalf;
        const int m_loc = wm * 64 + mi * 32 + row_l;
        const int n_loc = wn * 64 + ni * 32 + l32;
        float v = acc[mi][ni][reg];
        #pragma unroll
        for (int e = 0; e < EG; ++e)
          v += coefS[m_loc * EG + e] * biasS[e * 128 + n_loc];
        po[(size_t)(bm0 + m_loc) * NOUT + bn0 + n_loc] = v;
      }
}

// ---- expand: x_next = f16( j<64 ? z : elu(part0+part1) ), vectorized x4 ----
__global__ __launch_bounds__(256) void expand_x(
    const float* __restrict__ part,   // [2][B_][HID]
    const float* __restrict__ z,
    _Float16* __restrict__ xn)        // [B_][IN2]
{
  const int idx4 = blockIdx.x * 256 + threadIdx.x;   // B_*IN2/4 exact
  const int b = idx4 / (IN2 / 4), j = (idx4 - b * (IN2 / 4)) * 4;
  half4 o;
  if (j < LAT) {
    f32x4 v = *(const f32x4*)(z + (size_t)b * LAT + j);
    #pragma unroll
    for (int q = 0; q < 4; ++q) o[q] = (_Float16)v[q];
  } else {
    const int h = j - LAT;
    f32x4 v0 = *(const f32x4*)(part + (size_t)b * HID + h);
    f32x4 v1 = *(const f32x4*)(part + (size_t)B_ * HID + (size_t)b * HID + h);
    #pragma unroll
    for (int q = 0; q < 4; ++q) o[q] = (_Float16)elu(v0[q] + v1[q]);
  }
  *(half4*)(xn + (size_t)b * IN2 + j) = o;
}

// ---- final: out = sum_s part[s], vectorized x4 ----
__global__ __launch_bounds__(256) void final_out(
    const float* __restrict__ part,   // [4][B_][FRAME]
    float* __restrict__ out)
{
  const int idx4 = (blockIdx.x * 256 + threadIdx.x) * 4;   // B_*FRAME exact
  f32x4 v = *(const f32x4*)(part + idx4);
  #pragma unroll
  for (int s = 1; s < 4; ++s) {
    f32x4 p = *(const f32x4*)(part + (size_t)s * B_ * FRAME + idx4);
    #pragma unroll
    for (int q = 0; q < 4; ++q) v[q] += p[q];
  }
  *(f32x4*)(out + idx4) = v;
}

// ============================ launch ============================

extern "C" void kernel_launch(void* const* d_in, const int* in_sizes, int n_in,
                              void* d_out, int out_size, void* d_ws, size_t ws_size,
                              hipStream_t stream)
{
  const float* z   = (const float*)d_in[0];
  const float* c   = (const float*)d_in[1];
  const float* w0  = (const float*)d_in[2];
  const float* b0  = (const float*)d_in[3];
  const float* w1  = (const float*)d_in[4];
  const float* b1  = (const float*)d_in[5];
  const float* w2  = (const float*)d_in[6];
  const float* b2  = (const float*)d_in[7];
  const float* gw1 = (const float*)d_in[8];
  const float* gb1 = (const float*)d_in[9];
  const float* gw2 = (const float*)d_in[10];
  const float* gb2 = (const float*)d_in[11];
  const float* gw3 = (const float*)d_in[12];
  const float* gb3 = (const float*)d_in[13];
  float* out = (float*)d_out;
  char* ws = (char*)d_ws;

  // workspace layout, total 92,585,984 bytes (< proven 122,814,464)
  float*    coef = (float*)    (ws + 0);           //   131,072
  _Float16* x1   = (_Float16*) (ws + 131072);      // 4,718,592
  _Float16* x2   = (_Float16*) (ws + 4849664);     // 8,912,896
  _Float16* x3   = (_Float16*) (ws + 13762560);    // 8,912,896
  _Float16* Wt0  = (_Float16*) (ws + 22675456);    // 9,437,184
  _Float16* Wt1  = (_Float16*) (ws + 32112640);    // 17,825,792
  _Float16* Wt2  = (_Float16*) (ws + 49938432);    // 8,912,896
  float*    part = (float*)    (ws + 58851328);    // 33,554,432
  _Float16* gw1T = (_Float16*) (ws + 92405760);    //   147,456
  _Float16* gw2T = (_Float16*) (ws + 92553216);    //    32,768

  prep_weights<<<4438, 256, 0, stream>>>(w0, w1, w2, gw1, gw2,
                                         Wt0, Wt1, Wt2, gw1T, gw2T);
  gate_mfma<<<64, 256, 0, stream>>>(z, c, gw1T, gw2T, gb1, gb2, gw3, gb3, coef);
  build_x1<<<(B_ * IN1 / 4) / 256, 256, 0, stream>>>(z, c, x1);

  // layer 1: K=576, N=1024, expert-split 2 x EG4
  gemm_moe<IN1, HID, 4><<<dim3(32, 8, 2), 256, 0, stream>>>(x1, Wt0, coef, b0, part);
  expand_x<<<(B_ * IN2 / 4) / 256, 256, 0, stream>>>(part, z, x2);

  // layer 2: K=1088, N=1024, expert-split 2 x EG4
  gemm_moe<IN2, HID, 4><<<dim3(32, 8, 2), 256, 0, stream>>>(x2, Wt1, coef, b1, part);
  expand_x<<<(B_ * IN2 / 4) / 256, 256, 0, stream>>>(part, z, x3);

  // layer 3: K=1088, N=512, expert-split 4 x EG2
  gemm_moe<IN2, FRAME, 2><<<dim3(32, 4, 4), 256, 0, stream>>>(x3, Wt2, coef, b2, part);
  final_out<<<(B_ * FRAME / 4) / 256, 256, 0, stream>>>(part, out);
}

// Round 8
// 341.878 us; speedup vs baseline: 1.5227x; 1.0430x over previous
//
#include <hip/hip_runtime.h>
#include <cstdint>
#include <cstddef>

#define B_    4096
#define LAT   64
#define FRAME 512
#define HID   1024
#define NE    8
#define GH    128
#define IN1   576   // LAT + FRAME
#define IN2   1088  // LAT + HID

typedef _Float16 half8 __attribute__((ext_vector_type(8)));
typedef _Float16 half4 __attribute__((ext_vector_type(4)));
typedef float  f32x4  __attribute__((ext_vector_type(4)));

// async global->LDS, 16B per lane; LDS dest = wave-uniform base + lane*16
__device__ inline void async16(const void* g, void* l) {
  __builtin_amdgcn_global_load_lds(
      (__attribute__((address_space(1))) void*)(void*)g,
      (__attribute__((address_space(3))) void*)l, 16, 0, 0);
}

__device__ inline float elu(float v) { return v > 0.f ? v : expm1f(v); }

// ---- unified weight prep: all 5 transpose+casts (fp32 [K][N] -> f16 [N][K]) ----
// 64x64 tiles; float4 global loads, half4 global writes.
// blocks: w0 1152 | w1 2176 | w2 1088 | gw1 18 | gw2 4
__global__ __launch_bounds__(256) void prep_weights(
    const float* __restrict__ w0, const float* __restrict__ w1,
    const float* __restrict__ w2, const float* __restrict__ gw1,
    const float* __restrict__ gw2,
    _Float16* __restrict__ Wt0, _Float16* __restrict__ Wt1,
    _Float16* __restrict__ Wt2, _Float16* __restrict__ gw1T,
    _Float16* __restrict__ gw2T)
{
  __shared__ float t[64][65];
  int bid = blockIdx.x;
  const float* in; _Float16* out; int K, N, kt, nt;
  if (bid < 1152) {
    const int e = bid / 144, rem = bid % 144;
    K = IN1; N = HID; kt = rem / 16; nt = rem % 16;
    in = w0 + (size_t)e * K * N; out = Wt0 + (size_t)e * N * K;
  } else if (bid < 3328) {
    const int i = bid - 1152, e = i / 272, rem = i % 272;
    K = IN2; N = HID; kt = rem / 16; nt = rem % 16;
    in = w1 + (size_t)e * K * N; out = Wt1 + (size_t)e * N * K;
  } else if (bid < 4416) {
    const int i = bid - 3328, e = i / 136, rem = i % 136;
    K = IN2; N = FRAME; kt = rem / 8; nt = rem % 8;
    in = w2 + (size_t)e * K * N; out = Wt2 + (size_t)e * N * K;
  } else if (bid < 4434) {
    const int i = bid - 4416;
    K = IN1; N = GH; kt = i / 2; nt = i % 2;
    in = gw1; out = gw1T;
  } else {
    const int i = bid - 4434;
    K = GH; N = GH; kt = i / 2; nt = i % 2;
    in = gw2; out = gw2T;
  }
  const int k0 = kt * 64, n0 = nt * 64;
  const int lr = threadIdx.x >> 4;          // 0..15
  const int lc = (threadIdx.x & 15) * 4;    // 0..60
  #pragma unroll
  for (int rr = 0; rr < 4; ++rr) {
    const int k = rr * 16 + lr;
    f32x4 v = *(const f32x4*)(in + (size_t)(k0 + k) * N + n0 + lc);
    t[k][lc] = v[0]; t[k][lc + 1] = v[1]; t[k][lc + 2] = v[2]; t[k][lc + 3] = v[3];
  }
  __syncthreads();
  #pragma unroll
  for (int rr = 0; rr < 4; ++rr) {
    const int n = rr * 16 + lr;
    half4 o;
    #pragma unroll
    for (int q = 0; q < 4; ++q) o[q] = (_Float16)t[lc + q][n];
    *(half4*)(out + (size_t)(n0 + n) * K + k0 + lc) = o;
  }
}

// ---------------- gate MLP via f16 MFMA -> coef [B, 8] fp32 ----------------
// 64 blocks x 256 thr; block = 64 rows; wave w owns rows w*16..w*16+15.
__global__ __launch_bounds__(256) void gate_mfma(
    const float* __restrict__ z, const float* __restrict__ c,
    const _Float16* __restrict__ gw1T,   // [128][576]
    const _Float16* __restrict__ gw2T,   // [128][128]
    const float* __restrict__ gb1, const float* __restrict__ gb2,
    const float* __restrict__ gw3, const float* __restrict__ gb3,
    float* __restrict__ coef)
{
  __shared__ _Float16 h_lds[64][136];
  __shared__ float    h2_lds[64][129];
  __shared__ float    gw3s[128 * 8];
  const int tid = threadIdx.x;
  const int wave = tid >> 6, lane = tid & 63;
  const int quad = lane >> 4, l16 = lane & 15;
  const int r0 = blockIdx.x * 64;

  for (int i = tid; i < 128 * 8; i += 256) gw3s[i] = gw3[i];

  // layer 1: [64 x 576] @ gw1 -> h [64 x 128]
  f32x4 acc[8];
  #pragma unroll
  for (int nt = 0; nt < 8; ++nt)
    #pragma unroll
    for (int r = 0; r < 4; ++r) acc[nt][r] = 0.f;

  #pragma unroll 2
  for (int s = 0; s < 18; ++s) {
    const int k0 = s * 32;
    half8 af;
    {
      const size_t row = r0 + wave * 16 + l16;
      const float* src = (k0 < LAT) ? z + row * LAT + k0 + quad * 8
                                    : c + row * FRAME + (k0 - LAT) + quad * 8;
      f32x4 lo = *(const f32x4*)src, hi = *(const f32x4*)(src + 4);
      #pragma unroll
      for (int j = 0; j < 4; ++j) { af[j] = (_Float16)lo[j]; af[j + 4] = (_Float16)hi[j]; }
    }
    half8 bfr[8];
    #pragma unroll
    for (int nt = 0; nt < 8; ++nt)
      bfr[nt] = *(const half8*)(gw1T + (size_t)(nt * 16 + l16) * 576 + k0 + quad * 8);
    #pragma unroll
    for (int nt = 0; nt < 8; ++nt)
      acc[nt] = __builtin_amdgcn_mfma_f32_16x16x32_f16(af, bfr[nt], acc[nt], 0, 0, 0);
  }
  #pragma unroll
  for (int nt = 0; nt < 8; ++nt)
    #pragma unroll
    for (int r = 0; r < 4; ++r) {
      const int rowl = wave * 16 + quad * 4 + r;
      const int col = nt * 16 + l16;
      h_lds[rowl][col] = (_Float16)elu(acc[nt][r] + gb1[col]);
    }
  __syncthreads();

  // layer 2: h @ gw2 -> h2 [64 x 128]
  f32x4 acc2[8];
  #pragma unroll
  for (int nt = 0; nt < 8; ++nt)
    #pragma unroll
    for (int r = 0; r < 4; ++r) acc2[nt][r] = 0.f;
  #pragma unroll
  for (int s = 0; s < 4; ++s) {
    const int k0 = s * 32;
    half8 af = *(const half8*)&h_lds[wave * 16 + l16][k0 + quad * 8];
    half8 bfr[8];
    #pragma unroll
    for (int nt = 0; nt < 8; ++nt)
      bfr[nt] = *(const half8*)(gw2T + (size_t)(nt * 16 + l16) * 128 + k0 + quad * 8);
    #pragma unroll
    for (int nt = 0; nt < 8; ++nt)
      acc2[nt] = __builtin_amdgcn_mfma_f32_16x16x32_f16(af, bfr[nt], acc2[nt], 0, 0, 0);
  }
  #pragma unroll
  for (int nt = 0; nt < 8; ++nt)
    #pragma unroll
    for (int r = 0; r < 4; ++r) {
      const int rowl = wave * 16 + quad * 4 + r;
      const int col = nt * 16 + l16;
      h2_lds[rowl][col] = elu(acc2[nt][r] + gb2[col]);
    }
  __syncthreads();

  // layer 3 + softmax: 4 threads/row, 2 experts each
  {
    const int row = tid >> 2, q = tid & 3;
    float l2v[2] = { gb3[2 * q], gb3[2 * q + 1] };
    for (int k = 0; k < 128; ++k) {
      const float hv = h2_lds[row][k];
      l2v[0] += hv * gw3s[k * 8 + 2 * q];
      l2v[1] += hv * gw3s[k * 8 + 2 * q + 1];
    }
    float m = fmaxf(l2v[0], l2v[1]);
    m = fmaxf(m, __shfl_xor(m, 1));
    m = fmaxf(m, __shfl_xor(m, 2));
    float e0 = expf(l2v[0] - m), e1 = expf(l2v[1] - m);
    float s = e0 + e1;
    s += __shfl_xor(s, 1);
    s += __shfl_xor(s, 2);
    const float inv = 1.f / s;
    float2 o = { e0 * inv, e1 * inv };
    *(float2*)&coef[(size_t)(r0 + row) * NE + 2 * q] = o;
  }
}

// ---- x1 f16 = [z | c], vectorized x4 ----
__global__ __launch_bounds__(256) void build_x1(
    const float* __restrict__ z, const float* __restrict__ c,
    _Float16* __restrict__ x1)
{
  const int idx4 = blockIdx.x * 256 + threadIdx.x;   // B_*IN1/4 exact
  const int b = idx4 / (IN1 / 4), j = (idx4 - b * (IN1 / 4)) * 4;
  f32x4 v = (j < LAT) ? *(const f32x4*)(z + (size_t)b * LAT + j)
                      : *(const f32x4*)(c + (size_t)b * FRAME + (j - LAT));
  half4 o;
  #pragma unroll
  for (int q = 0; q < 4; ++q) o[q] = (_Float16)v[q];
  *(half4*)(x1 + (size_t)b * IN1 + j) = o;
}

// -------- MoE GEMM (r6-verified config): 16x16x32 f16, coef folded into A --------
// A staged once per k0 (reused across EG experts); B double-buffered.
// part[z] = sum_{e in group} coef_e*(X@W_e + bias_e)
template<int KDIM, int NOUT, int EG>
__global__ __launch_bounds__(256, 2) void gemm_moe(
    const _Float16* __restrict__ X,     // [B][KDIM]
    const _Float16* __restrict__ Wt,    // [NE][NOUT][KDIM]
    const float* __restrict__ coef,     // [B][8]
    const float* __restrict__ bias,     // [8][NOUT]
    float* __restrict__ part)           // [ESPLIT][B][NOUT]
{
  __shared__ __align__(16) _Float16 As[128 * 64];
  __shared__ __align__(16) _Float16 Bs[2][128 * 64];
  __shared__ float coefS[128 * EG];
  __shared__ float biasS[EG * 128];

  const int tid = threadIdx.x;
  const int wave = tid >> 6, lane = tid & 63;
  const int wm = wave & 1, wn = wave >> 1;
  const int quad = lane >> 4, l16 = lane & 15;
  const int bm0 = blockIdx.x * 128, bn0 = blockIdx.y * 128;
  const int ebase = blockIdx.z * EG;

  for (int i = tid; i < 128 * EG; i += 256)
    coefS[i] = coef[(size_t)(bm0 + i / EG) * NE + ebase + (i % EG)];
  for (int i = tid; i < EG * 128; i += 256)
    biasS[i] = bias[(size_t)(ebase + (i >> 7)) * NOUT + bn0 + (i & 127)];
  __syncthreads();

  // per-lane coef for A-scaling: A-fragment row = wm*64 + mi*16 + l16
  _Float16 ch[4][EG];
  #pragma unroll
  for (int mi = 0; mi < 4; ++mi)
    #pragma unroll
    for (int e = 0; e < EG; ++e)
      ch[mi][e] = (_Float16)coefS[(wm * 64 + mi * 16 + l16) * EG + e];

  f32x4 acc[4][4];
  #pragma unroll
  for (int mi = 0; mi < 4; ++mi)
    #pragma unroll
    for (int ni = 0; ni < 4; ++ni)
      #pragma unroll
      for (int r = 0; r < 4; ++r) acc[mi][ni][r] = 0.f;

  const int srow  = wave * 8 + (lane >> 3);                  // + it*32
  const int skoff = (((lane & 7) ^ ((lane >> 3) & 7)) * 8);  // swizzled src granule

  constexpr int K0S = KDIM / 64;
  for (int k0i = 0; k0i < K0S; ++k0i) {
    const int k0 = k0i * 64;
    // stage A (once per k0) and B for first expert of the group
    #pragma unroll
    for (int it = 0; it < 4; ++it)
      async16(X + (size_t)(bm0 + it * 32 + srow) * KDIM + k0 + skoff,
              &As[it * 2048 + wave * 512]);
    {
      const size_t eoff = (size_t)ebase * NOUT * KDIM;
      #pragma unroll
      for (int it = 0; it < 4; ++it)
        async16(Wt + eoff + (size_t)(bn0 + it * 32 + srow) * KDIM + k0 + skoff,
                &Bs[0][it * 2048 + wave * 512]);
    }
    __syncthreads();

    // A fragments for this k0, reused across the expert group
    half8 af[2][4];
    #pragma unroll
    for (int ks = 0; ks < 2; ++ks)
      #pragma unroll
      for (int mi = 0; mi < 4; ++mi) {
        const int r = wm * 64 + mi * 16 + l16;
        const int g = (ks * 4 + quad) ^ (r & 7);
        af[ks][mi] = *(const half8*)&As[r * 64 + g * 8];
      }

    #pragma unroll
    for (int eo = 0; eo < EG; ++eo) {
      if (eo + 1 < EG) {   // prefetch next expert's B tile into other buffer
        const size_t eoff = (size_t)(ebase + eo + 1) * NOUT * KDIM;
        #pragma unroll
        for (int it = 0; it < 4; ++it)
          async16(Wt + eoff + (size_t)(bn0 + it * 32 + srow) * KDIM + k0 + skoff,
                  &Bs[(eo + 1) & 1][it * 2048 + wave * 512]);
      }
      const _Float16* bsrc = Bs[eo & 1];
      #pragma unroll
      for (int ks = 0; ks < 2; ++ks) {
        half8 bv[4];
        #pragma unroll
        for (int ni = 0; ni < 4; ++ni) {
          const int r = wn * 64 + ni * 16 + l16;
          const int g = (ks * 4 + quad) ^ (r & 7);
          bv[ni] = *(const half8*)&bsrc[r * 64 + g * 8];
        }
        #pragma unroll
        for (int mi = 0; mi < 4; ++mi) {
          const half8 afs = af[ks][mi] * ch[mi][eo];
          #pragma unroll
          for (int ni = 0; ni < 4; ++ni)
            acc[mi][ni] = __builtin_amdgcn_mfma_f32_16x16x32_f16(
                afs, bv[ni], acc[mi][ni], 0, 0, 0);
        }
      }
      __syncthreads();   // protects Bs reuse and As for next k0's staging
    }
  }

  // epilogue: + group's coef@bias; write partial (deterministic).
  // 16x16 C/D layout: col = l16, row = quad*4 + r
  float* po = part + (size_t)blockIdx.z * B_ * NOUT;
  #pragma unroll
  for (int mi = 0; mi < 4; ++mi)
    #pragma unroll
    for (int r = 0; r < 4; ++r) {
      const int m_loc = wm * 64 + mi * 16 + quad * 4 + r;
      #pragma unroll
      for (int ni = 0; ni < 4; ++ni) {
        const int n_loc = wn * 64 + ni * 16 + l16;
        float v = acc[mi][ni][r];
        #pragma unroll
        for (int e = 0; e < EG; ++e)
          v += coefS[m_loc * EG + e] * biasS[e * 128 + n_loc];
        po[(size_t)(bm0 + m_loc) * NOUT + bn0 + n_loc] = v;
      }
    }
}

// ---- expand: x_next = f16( j<64 ? z : elu(part0+part1) ), vectorized x4 ----
__global__ __launch_bounds__(256) void expand_x(
    const float* __restrict__ part,   // [2][B_][HID]
    const float* __restrict__ z,
    _Float16* __restrict__ xn)        // [B_][IN2]
{
  const int idx4 = blockIdx.x * 256 + threadIdx.x;   // B_*IN2/4 exact
  const int b = idx4 / (IN2 / 4), j = (idx4 - b * (IN2 / 4)) * 4;
  half4 o;
  if (j < LAT) {
    f32x4 v = *(const f32x4*)(z + (size_t)b * LAT + j);
    #pragma unroll
    for (int q = 0; q < 4; ++q) o[q] = (_Float16)v[q];
  } else {
    const int h = j - LAT;
    f32x4 v0 = *(const f32x4*)(part + (size_t)b * HID + h);
    f32x4 v1 = *(const f32x4*)(part + (size_t)B_ * HID + (size_t)b * HID + h);
    #pragma unroll
    for (int q = 0; q < 4; ++q) o[q] = (_Float16)elu(v0[q] + v1[q]);
  }
  *(half4*)(xn + (size_t)b * IN2 + j) = o;
}

// ---- final: out = sum_s part[s], vectorized x4 ----
__global__ __launch_bounds__(256) void final_out(
    const float* __restrict__ part,   // [4][B_][FRAME]
    float* __restrict__ out)
{
  const int idx4 = (blockIdx.x * 256 + threadIdx.x) * 4;   // B_*FRAME exact
  f32x4 v = *(const f32x4*)(part + idx4);
  #pragma unroll
  for (int s = 1; s < 4; ++s) {
    f32x4 p = *(const f32x4*)(part + (size_t)s * B_ * FRAME + idx4);
    #pragma unroll
    for (int q = 0; q < 4; ++q) v[q] += p[q];
  }
  *(f32x4*)(out + idx4) = v;
}

// ============================ launch ============================

extern "C" void kernel_launch(void* const* d_in, const int* in_sizes, int n_in,
                              void* d_out, int out_size, void* d_ws, size_t ws_size,
                              hipStream_t stream)
{
  const float* z   = (const float*)d_in[0];
  const float* c   = (const float*)d_in[1];
  const float* w0  = (const float*)d_in[2];
  const float* b0  = (const float*)d_in[3];
  const float* w1  = (const float*)d_in[4];
  const float* b1  = (const float*)d_in[5];
  const float* w2  = (const float*)d_in[6];
  const float* b2  = (const float*)d_in[7];
  const float* gw1 = (const float*)d_in[8];
  const float* gb1 = (const float*)d_in[9];
  const float* gw2 = (const float*)d_in[10];
  const float* gb2 = (const float*)d_in[11];
  const float* gw3 = (const float*)d_in[12];
  const float* gb3 = (const float*)d_in[13];
  float* out = (float*)d_out;
  char* ws = (char*)d_ws;

  // workspace layout, total 92,585,984 bytes (< proven 122,814,464)
  float*    coef = (float*)    (ws + 0);           //   131,072
  _Float16* x1   = (_Float16*) (ws + 131072);      // 4,718,592
  _Float16* x2   = (_Float16*) (ws + 4849664);     // 8,912,896
  _Float16* x3   = (_Float16*) (ws + 13762560);    // 8,912,896
  _Float16* Wt0  = (_Float16*) (ws + 22675456);    // 9,437,184
  _Float16* Wt1  = (_Float16*) (ws + 32112640);    // 17,825,792
  _Float16* Wt2  = (_Float16*) (ws + 49938432);    // 8,912,896
  float*    part = (float*)    (ws + 58851328);    // 33,554,432
  _Float16* gw1T = (_Float16*) (ws + 92405760);    //   147,456
  _Float16* gw2T = (_Float16*) (ws + 92553216);    //    32,768

  prep_weights<<<4438, 256, 0, stream>>>(w0, w1, w2, gw1, gw2,
                                         Wt0, Wt1, Wt2, gw1T, gw2T);
  gate_mfma<<<64, 256, 0, stream>>>(z, c, gw1T, gw2T, gb1, gb2, gw3, gb3, coef);
  build_x1<<<(B_ * IN1 / 4) / 256, 256, 0, stream>>>(z, c, x1);

  // layer 1: K=576, N=1024, expert-split 2 x EG4
  gemm_moe<IN1, HID, 4><<<dim3(32, 8, 2), 256, 0, stream>>>(x1, Wt0, coef, b0, part);
  expand_x<<<(B_ * IN2 / 4) / 256, 256, 0, stream>>>(part, z, x2);

  // layer 2: K=1088, N=1024, expert-split 2 x EG4
  gemm_moe<IN2, HID, 4><<<dim3(32, 8, 2), 256, 0, stream>>>(x2, Wt1, coef, b1, part);
  expand_x<<<(B_ * IN2 / 4) / 256, 256, 0, stream>>>(part, z, x3);

  // layer 3: K=1088, N=512, expert-split 4 x EG2
  gemm_moe<IN2, FRAME, 2><<<dim3(32, 4, 4), 256, 0, stream>>>(x3, Wt2, coef, b2, part);
  final_out<<<(B_ * FRAME / 4) / 256, 256, 0, stream>>>(part, out);
}